// Round 7
// baseline (492.307 us; speedup 1.0000x reference)
//
#include <hip/hip_runtime.h>
#include <hip/hip_bf16.h>

// LengthRegulator on MI355X — R7: LN fused into convs (full-channel tiles).
// conv_ln_fused<MODE>: block = 384h x 32t, 4 waves (96h x 32t each),
// K staged 32-wide via global_load_lds (X once per c, W per (c,k)).
// MODE 0: + bias,LN,ReLU -> f16 splits to H1t (LDS-transposed coalesced).
// MODE 1: + bias,LN,ReLU,dot(Wl)+bl,ReLU -> z.  ln_split/ln_proj deleted;
// h_raw eliminated. prep_w/prep_x/dur_scan/gather unchanged from R6.

#define BB 32
#define HHD 384
#define TTOT 1024
#define MAXL 4096

typedef _Float16 half8 __attribute__((ext_vector_type(8)));
typedef float floatx4 __attribute__((ext_vector_type(4)));

// ---------------------------------------------------------------------------
// prep_w: W[h][hi][k] fp32 -> Wq[s] f16, layout e = ((c*3+k)*384 + h)*32 + d,
// where c = hi/32, d = hi%32. Split: hi = f16(w), lo = f16((w-hi)*2048).
__global__ void prep_w_kernel(const float* __restrict__ W1,
                              const float* __restrict__ W2,
                              _Float16* __restrict__ q1h, _Float16* __restrict__ q1l,
                              _Float16* __restrict__ q2h, _Float16* __restrict__ q2l) {
    const int e = blockIdx.x * 256 + threadIdx.x;     // < 442368
    const float* W = blockIdx.y ? W2 : W1;
    _Float16* oh = blockIdx.y ? q2h : q1h;
    _Float16* ol = blockIdx.y ? q2l : q1l;
    const int d  = e & 31;
    const int m  = (e >> 5) % 384;
    const int ck = e / (32 * 384);
    const int c  = ck / 3, k = ck - 3 * c;
    const float w = W[(size_t)m * 1152 + (size_t)(32 * c + d) * 3 + k];
    const _Float16 hi = (_Float16)w;
    oh[e] = hi;
    ol[e] = (_Float16)((w - (float)hi) * 2048.0f);
}

// ---------------------------------------------------------------------------
// prep_x: x[b][h][t] fp32 -> Xt1/Xt2 f16 [b][t][384] (transposed + split). [R6]
__global__ void prep_x_kernel(const float* __restrict__ X,
                              _Float16* __restrict__ o1,
                              _Float16* __restrict__ o2) {
    __shared__ float Ls[64][65];
    const int h0 = blockIdx.x * 64;
    const int t0 = blockIdx.y * 64;
    const int b  = blockIdx.z;
    const int tid = threadIdx.x;
    const int tl = tid & 63, hq = tid >> 6;
    const float* Xb = X + (size_t)b * HHD * TTOT;
#pragma unroll
    for (int i = 0; i < 16; ++i) {
        const int h = i * 4 + hq;
        Ls[tl][h] = Xb[(size_t)(h0 + h) * TTOT + t0 + tl];
    }
    __syncthreads();
#pragma unroll
    for (int i = 0; i < 16; ++i) {
        const int t = i * 4 + hq;
        const float v = Ls[t][tl];
        const _Float16 a = (_Float16)v;
        const size_t o = ((size_t)b * TTOT + t0 + t) * HHD + h0 + tl;
        o1[o] = a;
        o2[o] = (_Float16)((v - (float)a) * 2048.0f);
    }
}

// ---------------------------------------------------------------------------
// conv_ln_fused. LDS map (halfs): W [2 spl][384 m][32 d] @0 (24576),
// X [2 spl][34 t][32 d] @24576 (2176); total 26752 = 53,504 B -> 3 blocks/CU.
// Epilogue reuse (f32 view): stats [0..256), zpart [256..384), Lt @512 [32][392].
// C/D layout (verified R2/R6): m = (lane>>4)*4 + reg, t = lane&15 per 16x16 tile.
template <int MODE>
__launch_bounds__(256, 2)
__global__ void conv_ln_fused(const _Float16* __restrict__ Bh,  // [b][t][384] hi
                              const _Float16* __restrict__ Bl,  // lo
                              const _Float16* __restrict__ Ah,  // Wq hi
                              const _Float16* __restrict__ Al,  // Wq lo
                              const float* __restrict__ bias,
                              const float* __restrict__ gain,
                              const float* __restrict__ beta,
                              const float* __restrict__ Wl,     // MODE 1
                              const float* __restrict__ blp,    // MODE 1
                              _Float16* __restrict__ O1,        // MODE 0: H1t hi
                              _Float16* __restrict__ O2,        // MODE 0: H1t lo
                              float* __restrict__ zb) {         // MODE 1
    __shared__ __align__(16) _Float16 sm[26752];
    const int tid  = threadIdx.x;
    const int lane = tid & 63, w = tid >> 6;
    const int l15 = lane & 15, g4 = lane >> 4;
    const int tt = blockIdx.x;          // t-tile [0,32)
    const int t0 = tt * 32;
    const int b  = blockIdx.y;

    floatx4 ahh[6][2], axx[6][2];
#pragma unroll
    for (int mt = 0; mt < 6; ++mt)
#pragma unroll
        for (int nt = 0; nt < 2; ++nt) {
            ahh[mt][nt] = (floatx4){0.f, 0.f, 0.f, 0.f};
            axx[mt][nt] = (floatx4){0.f, 0.f, 0.f, 0.f};
        }

    const size_t xbase = (size_t)b * TTOT * HHD;
    const half8 hz = {0, 0, 0, 0, 0, 0, 0, 0};

    // X slot decomposition (272 slots of 16 B): pass0 e=tid, pass1 e=256+tid (tid<16).
    // e: s = e>=136, r = e - s*136, j = r>>2, q = r&3; row gt = t0-1+j clamped.
    for (int c = 0; c < 12; ++c) {
        __syncthreads();                      // prev k=2 reads done
        {   // stage X chunk (channels 32c..32c+31)
            int e = tid;
            if (e < 272) {
                const int s = (e >= 136);
                const int r = e - s * 136;
                const int gtc = min(max(t0 - 1 + (r >> 2), 0), TTOT - 1);
                const _Float16* src = (s ? Bl : Bh) + xbase +
                    (size_t)gtc * HHD + c * 32 + ((r & 3) << 3);
                __builtin_amdgcn_global_load_lds((const unsigned int*)src,
                    (unsigned int*)&sm[24576 + e * 8], 16, 0, 0);
            }
            e = 256 + tid;
            if (tid < 16) {
                const int r = e - 136;        // s==1
                const int gtc = min(max(t0 - 1 + (r >> 2), 0), TTOT - 1);
                const _Float16* src = Bl + xbase +
                    (size_t)gtc * HHD + c * 32 + ((r & 3) << 3);
                __builtin_amdgcn_global_load_lds((const unsigned int*)src,
                    (unsigned int*)&sm[24576 + e * 8], 16, 0, 0);
            }
        }
        for (int k = 0; k < 3; ++k) {
            if (k > 0) __syncthreads();       // prev k's reads done
            {   // stage W chunk (c,k): contiguous 12288 halfs per split
                const size_t wo = (size_t)(c * 3 + k) * 12288;
#pragma unroll
                for (int it = 0; it < 6; ++it) {
                    const int r = tid + it * 256;
                    __builtin_amdgcn_global_load_lds(
                        (const unsigned int*)(Ah + wo + r * 8),
                        (unsigned int*)&sm[r * 8], 16, 0, 0);
                }
#pragma unroll
                for (int it = 0; it < 6; ++it) {
                    const int r = tid + it * 256;
                    __builtin_amdgcn_global_load_lds(
                        (const unsigned int*)(Al + wo + r * 8),
                        (unsigned int*)&sm[12288 + r * 8], 16, 0, 0);
                }
            }
            __syncthreads();                  // staging drained

            half8 ah[6], al[6], bh[2], bl[2];
#pragma unroll
            for (int mt = 0; mt < 6; ++mt) {
                const int m = w * 96 + mt * 16 + l15;
                ah[mt] = *(const half8*)&sm[m * 32 + g4 * 8];
                al[mt] = *(const half8*)&sm[12288 + m * 32 + g4 * 8];
            }
#pragma unroll
            for (int nt = 0; nt < 2; ++nt) {
                const int j = nt * 16 + l15 + k;
                bh[nt] = *(const half8*)&sm[24576 + j * 32 + g4 * 8];
                bl[nt] = *(const half8*)&sm[24576 + 1088 + j * 32 + g4 * 8];
            }
            if (tt == 0 && k == 0 && l15 == 0)  { bh[0] = hz; bl[0] = hz; }  // t=-1
            if (tt == 31 && k == 2 && l15 == 15) { bh[1] = hz; bl[1] = hz; } // t=1024
#pragma unroll
            for (int mt = 0; mt < 6; ++mt)
#pragma unroll
                for (int nt = 0; nt < 2; ++nt) {
                    ahh[mt][nt] = __builtin_amdgcn_mfma_f32_16x16x32_f16(
                        ah[mt], bh[nt], ahh[mt][nt], 0, 0, 0);
                    axx[mt][nt] = __builtin_amdgcn_mfma_f32_16x16x32_f16(
                        ah[mt], bl[nt], axx[mt][nt], 0, 0, 0);
                    axx[mt][nt] = __builtin_amdgcn_mfma_f32_16x16x32_f16(
                        al[mt], bh[nt], axx[mt][nt], 0, 0, 0);
                }
        }
    }

    // ---- epilogue: recombine + bias; LN stats; normalize (+proj) ----
    __syncthreads();                          // all waves done reading sm
    float* st = (float*)sm;                   // stats [32 t][4 w][2]

#pragma unroll
    for (int mt = 0; mt < 6; ++mt) {
        const float4 bv = *(const float4*)&bias[w * 96 + mt * 16 + g4 * 4];
#pragma unroll
        for (int nt = 0; nt < 2; ++nt)
#pragma unroll
            for (int r = 0; r < 4; ++r)
                ahh[mt][nt][r] += axx[mt][nt][r] * (1.0f / 2048.0f) +
                                  ((const float*)&bv)[r];
    }
    float s0 = 0.f, ss0 = 0.f, s1 = 0.f, ss1 = 0.f;
#pragma unroll
    for (int mt = 0; mt < 6; ++mt)
#pragma unroll
        for (int r = 0; r < 4; ++r) {
            const float v0 = ahh[mt][0][r], v1 = ahh[mt][1][r];
            s0 += v0; ss0 += v0 * v0;
            s1 += v1; ss1 += v1 * v1;
        }
    s0 += __shfl_xor(s0, 16, 64); ss0 += __shfl_xor(ss0, 16, 64);
    s1 += __shfl_xor(s1, 16, 64); ss1 += __shfl_xor(ss1, 16, 64);
    s0 += __shfl_xor(s0, 32, 64); ss0 += __shfl_xor(ss0, 32, 64);
    s1 += __shfl_xor(s1, 32, 64); ss1 += __shfl_xor(ss1, 32, 64);
    if (g4 == 0) {
        st[(l15 * 4 + w) * 2]            = s0;
        st[(l15 * 4 + w) * 2 + 1]        = ss0;
        st[((16 + l15) * 4 + w) * 2]     = s1;
        st[((16 + l15) * 4 + w) * 2 + 1] = ss1;
    }
    __syncthreads();
    float mean[2], inv[2];
#pragma unroll
    for (int nt = 0; nt < 2; ++nt) {
        const int t = nt * 16 + l15;
        float s = 0.f, ss = 0.f;
#pragma unroll
        for (int wv = 0; wv < 4; ++wv) {
            s  += st[(t * 4 + wv) * 2];
            ss += st[(t * 4 + wv) * 2 + 1];
        }
        const float m = s * (1.0f / HHD);
        mean[nt] = m;
        inv[nt]  = rsqrtf(ss * (1.0f / HHD) - m * m + 1e-5f);
    }

    if constexpr (MODE == 0) {
        float* Lt = (float*)sm + 512;         // [32 t][392]
#pragma unroll
        for (int mt = 0; mt < 6; ++mt) {
            const int hb = w * 96 + mt * 16 + g4 * 4;
            const float4 ga = *(const float4*)&gain[hb];
            const float4 be = *(const float4*)&beta[hb];
#pragma unroll
            for (int nt = 0; nt < 2; ++nt) {
                const int t = nt * 16 + l15;
                float4 y;
#pragma unroll
                for (int r = 0; r < 4; ++r) {
                    float v = (ahh[mt][nt][r] - mean[nt]) * inv[nt] *
                              ((const float*)&ga)[r] + ((const float*)&be)[r];
                    ((float*)&y)[r] = fmaxf(v, 0.f);
                }
                *(float4*)&Lt[t * 392 + hb] = y;
            }
        }
        __syncthreads();
        // coalesced split-store: 1536 h8-chunks = [32 t][48 chunks]
#pragma unroll
        for (int i = 0; i < 6; ++i) {
            const int cc = tid + i * 256;
            const int row = cc / 48, hc = cc - row * 48;
            const float4 aq = *(const float4*)&Lt[row * 392 + hc * 8];
            const float4 bq = *(const float4*)&Lt[row * 392 + hc * 8 + 4];
            half8 vh, vl;
#pragma unroll
            for (int j = 0; j < 4; ++j) {
                const float f0 = ((const float*)&aq)[j];
                const float f1 = ((const float*)&bq)[j];
                const _Float16 a0 = (_Float16)f0, a1 = (_Float16)f1;
                vh[j]     = a0; vl[j]     = (_Float16)((f0 - (float)a0) * 2048.0f);
                vh[j + 4] = a1; vl[j + 4] = (_Float16)((f1 - (float)a1) * 2048.0f);
            }
            const size_t o = ((size_t)b * TTOT + t0 + row) * HHD + hc * 8;
            *(half8*)&O1[o] = vh;
            *(half8*)&O2[o] = vl;
        }
    } else {
        float zs0 = 0.f, zs1 = 0.f;
#pragma unroll
        for (int mt = 0; mt < 6; ++mt) {
            const int hb = w * 96 + mt * 16 + g4 * 4;
            const float4 ga = *(const float4*)&gain[hb];
            const float4 be = *(const float4*)&beta[hb];
            const float4 wl = *(const float4*)&Wl[hb];
#pragma unroll
            for (int r = 0; r < 4; ++r) {
                const float y0 = fmaxf((ahh[mt][0][r] - mean[0]) * inv[0] *
                    ((const float*)&ga)[r] + ((const float*)&be)[r], 0.f);
                const float y1 = fmaxf((ahh[mt][1][r] - mean[1]) * inv[1] *
                    ((const float*)&ga)[r] + ((const float*)&be)[r], 0.f);
                zs0 += y0 * ((const float*)&wl)[r];
                zs1 += y1 * ((const float*)&wl)[r];
            }
        }
        zs0 += __shfl_xor(zs0, 16, 64); zs1 += __shfl_xor(zs1, 16, 64);
        zs0 += __shfl_xor(zs0, 32, 64); zs1 += __shfl_xor(zs1, 32, 64);
        float* zp = (float*)sm + 256;         // [32 t][4 w]
        if (g4 == 0) {
            zp[l15 * 4 + w]        = zs0;
            zp[(16 + l15) * 4 + w] = zs1;
        }
        __syncthreads();
        if (tid < 32) {
            const float zsum = zp[tid * 4] + zp[tid * 4 + 1] +
                               zp[tid * 4 + 2] + zp[tid * 4 + 3];
            zb[b * TTOT + t0 + tid] = fmaxf(zsum + blp[0], 0.f);
        }
    }
}

// ---------------------------------------------------------------------------
// dur_scan: durations + per-batch inclusive scan. [R3]
__global__ void dur_scan_kernel(const float* __restrict__ z,
                                float* __restrict__ durOut,
                                int* __restrict__ cum) {
    __shared__ int sb[TTOT];
    const int b = blockIdx.x;
    const int t = threadIdx.x;
    const int d = (int)floorf(expf(z[b * TTOT + t]));
    durOut[b * TTOT + t] = (float)d;
    sb[t] = d;
    __syncthreads();
    for (int off = 1; off < TTOT; off <<= 1) {
        const int v = (t >= off) ? sb[t - off] : 0;
        __syncthreads();
        sb[t] += v;
        __syncthreads();
    }
    cum[b * TTOT + t] = sb[t];
}

// ---------------------------------------------------------------------------
// gather: searchsorted + masked gather. [R3]
__global__ void gather_kernel(const float* __restrict__ X,
                              const int* __restrict__ cum,
                              float* __restrict__ aligned) {
    __shared__ int cs[TTOT];
    const int b   = blockIdx.y;
    const int tid = threadIdx.x;
    for (int e = tid; e < TTOT; e += 256) cs[e] = cum[b * TTOT + e];
    __syncthreads();
    const int pos   = blockIdx.x * 256 + tid;
    const int total = cs[TTOT - 1];
    int lo = 0, hi = TTOT;
    while (lo < hi) {
        const int mid = (lo + hi) >> 1;
        if (cs[mid] <= pos) lo = mid + 1; else hi = mid;
    }
    const float vmul = (pos < total) ? 1.f : 0.f;
    const int idx = min(lo, TTOT - 1);
    const float* Xb = X + (size_t)b * HHD * TTOT;
    float* Ab = aligned + (size_t)b * HHD * MAXL;
#pragma unroll 4
    for (int h = 0; h < HHD; ++h)
        Ab[(size_t)h * MAXL + pos] = Xb[(size_t)h * TTOT + idx] * vmul;
}

// ---------------------------------------------------------------------------
extern "C" void kernel_launch(void* const* d_in, const int* in_sizes, int n_in,
                              void* d_out, int out_size, void* d_ws, size_t ws_size,
                              hipStream_t stream) {
    const float* x   = (const float*)d_in[0];
    const float* W1  = (const float*)d_in[1];
    const float* b1  = (const float*)d_in[2];
    const float* g1  = (const float*)d_in[3];
    const float* be1 = (const float*)d_in[4];
    const float* W2  = (const float*)d_in[5];
    const float* b2  = (const float*)d_in[6];
    const float* g2  = (const float*)d_in[7];
    const float* be2 = (const float*)d_in[8];
    const float* Wl  = (const float*)d_in[9];
    const float* bl  = (const float*)d_in[10];

    float* out     = (float*)d_out;
    float* durOut  = out;                        // [B*T]
    float* aligned = out + (size_t)BB * TTOT;    // [B*H*MAXL]

    char* ws = (char*)d_ws;
    const size_t wqB = (size_t)442368 * sizeof(_Float16);
    const size_t xtB = (size_t)BB * TTOT * HHD * sizeof(_Float16);
    _Float16* Wq1h = (_Float16*)(ws);
    _Float16* Wq1l = (_Float16*)(ws + wqB);
    _Float16* Wq2h = (_Float16*)(ws + 2 * wqB);
    _Float16* Wq2l = (_Float16*)(ws + 3 * wqB);
    _Float16* Xt1  = (_Float16*)(ws + 4 * wqB);
    _Float16* Xt2  = (_Float16*)(ws + 4 * wqB + xtB);
    _Float16* H1t1 = (_Float16*)(ws + 4 * wqB + 2 * xtB);
    _Float16* H1t2 = (_Float16*)(ws + 4 * wqB + 3 * xtB);
    float*    zb   = (float*)   (ws + 4 * wqB + 4 * xtB);
    int*      cum  = (int*)     (ws + 4 * wqB + 4 * xtB + (size_t)BB * TTOT * 4);

    prep_w_kernel<<<dim3(1728, 2), 256, 0, stream>>>(W1, W2, Wq1h, Wq1l, Wq2h, Wq2l);
    prep_x_kernel<<<dim3(6, 16, 32), 256, 0, stream>>>(x, Xt1, Xt2);
    conv_ln_fused<0><<<dim3(32, BB), 256, 0, stream>>>(
        Xt1, Xt2, Wq1h, Wq1l, b1, g1, be1, nullptr, nullptr, H1t1, H1t2, nullptr);
    conv_ln_fused<1><<<dim3(32, BB), 256, 0, stream>>>(
        H1t1, H1t2, Wq2h, Wq2l, b2, g2, be2, Wl, bl, nullptr, nullptr, zb);
    dur_scan_kernel<<<BB, TTOT, 0, stream>>>(zb, durOut, cum);
    gather_kernel<<<dim3(MAXL / 256, BB), 256, 0, stream>>>(x, cum, aligned);
}